// Round 6
// baseline (247.266 us; speedup 1.0000x reference)
//
#include <hip/hip_runtime.h>
#include <math.h>

#define BLOCK 256
#define GRID 1024
#define UNROLL 8

typedef float vfloat4 __attribute__((ext_vector_type(4)));

// Stage 1: each block consumes a CONTIGUOUS 32 KB chunk per buffer per outer
// iteration (UNROLL=8 x 256 threads x 16 B), 1024 blocks. nt loads: streamed-
// once data, no cache retention. 16 independent loads in flight per thread.
__global__ __launch_bounds__(BLOCK) void partial_sq_sum(
    const vfloat4* __restrict__ a, const vfloat4* __restrict__ b,
    float* __restrict__ partial, int n4) {
    const int chunk = UNROLL * BLOCK;          // 2048 float4 = 32 KB per block-iter
    const int outer_stride = GRID * chunk;     // 32 MB per grid-iter
    float acc0 = 0.0f, acc1 = 0.0f, acc2 = 0.0f, acc3 = 0.0f;
    for (int base = blockIdx.x * chunk + threadIdx.x;
         base + (UNROLL - 1) * BLOCK < n4; base += outer_stride) {
        vfloat4 x0 = __builtin_nontemporal_load(a + base);
        vfloat4 x1 = __builtin_nontemporal_load(a + base + BLOCK);
        vfloat4 x2 = __builtin_nontemporal_load(a + base + 2 * BLOCK);
        vfloat4 x3 = __builtin_nontemporal_load(a + base + 3 * BLOCK);
        vfloat4 x4 = __builtin_nontemporal_load(a + base + 4 * BLOCK);
        vfloat4 x5 = __builtin_nontemporal_load(a + base + 5 * BLOCK);
        vfloat4 x6 = __builtin_nontemporal_load(a + base + 6 * BLOCK);
        vfloat4 x7 = __builtin_nontemporal_load(a + base + 7 * BLOCK);
        vfloat4 y0 = __builtin_nontemporal_load(b + base);
        vfloat4 y1 = __builtin_nontemporal_load(b + base + BLOCK);
        vfloat4 y2 = __builtin_nontemporal_load(b + base + 2 * BLOCK);
        vfloat4 y3 = __builtin_nontemporal_load(b + base + 3 * BLOCK);
        vfloat4 y4 = __builtin_nontemporal_load(b + base + 4 * BLOCK);
        vfloat4 y5 = __builtin_nontemporal_load(b + base + 5 * BLOCK);
        vfloat4 y6 = __builtin_nontemporal_load(b + base + 6 * BLOCK);
        vfloat4 y7 = __builtin_nontemporal_load(b + base + 7 * BLOCK);
        vfloat4 d0 = x0 - y0;
        vfloat4 d1 = x1 - y1;
        vfloat4 d2 = x2 - y2;
        vfloat4 d3 = x3 - y3;
        vfloat4 d4 = x4 - y4;
        vfloat4 d5 = x5 - y5;
        vfloat4 d6 = x6 - y6;
        vfloat4 d7 = x7 - y7;
        acc0 += d0.x * d0.x + d0.y * d0.y + d0.z * d0.z + d0.w * d0.w;
        acc1 += d1.x * d1.x + d1.y * d1.y + d1.z * d1.z + d1.w * d1.w;
        acc2 += d2.x * d2.x + d2.y * d2.y + d2.z * d2.z + d2.w * d2.w;
        acc3 += d3.x * d3.x + d3.y * d3.y + d3.z * d3.z + d3.w * d3.w;
        acc0 += d4.x * d4.x + d4.y * d4.y + d4.z * d4.z + d4.w * d4.w;
        acc1 += d5.x * d5.x + d5.y * d5.y + d5.z * d5.z + d5.w * d5.w;
        acc2 += d6.x * d6.x + d6.y * d6.y + d6.z * d6.z + d6.w * d6.w;
        acc3 += d7.x * d7.x + d7.y * d7.y + d7.z * d7.z + d7.w * d7.w;
    }
    // tail for n4 not divisible by GRID*UNROLL*BLOCK (not taken at N=32M)
    int done = (n4 / outer_stride) * outer_stride;
    for (int i = done + blockIdx.x * chunk + threadIdx.x; i < n4; i += BLOCK) {
        vfloat4 x = __builtin_nontemporal_load(a + i);
        vfloat4 y = __builtin_nontemporal_load(b + i);
        vfloat4 d = x - y;
        acc0 += d.x * d.x + d.y * d.y + d.z * d.z + d.w * d.w;
    }
    float acc = (acc0 + acc1) + (acc2 + acc3);
    // wave-64 reduction
    #pragma unroll
    for (int off = 32; off > 0; off >>= 1)
        acc += __shfl_down(acc, off, 64);
    __shared__ float smem[BLOCK / 64];
    int lane = threadIdx.x & 63;
    int wave = threadIdx.x >> 6;
    if (lane == 0) smem[wave] = acc;
    __syncthreads();
    if (threadIdx.x == 0) {
        float s = 0.0f;
        #pragma unroll
        for (int w = 0; w < BLOCK / 64; ++w) s += smem[w];
        partial[blockIdx.x] = s;
    }
}

// Stage 2: one block sums the GRID partials, applies the exact-match
// element-0 correction ((0.8*d0)^2 - d0^2 iff d0 in {3,4,5,6}), divides by N.
__global__ __launch_bounds__(BLOCK) void finalize(
    const float* __restrict__ partial, int n_partial,
    const float* __restrict__ in0, const float* __restrict__ tg0,
    float* __restrict__ out, float inv_n) {
    float acc = 0.0f;
    for (int i = threadIdx.x; i < n_partial; i += BLOCK)
        acc += partial[i];
    #pragma unroll
    for (int off = 32; off > 0; off >>= 1)
        acc += __shfl_down(acc, off, 64);
    __shared__ float smem[BLOCK / 64];
    int lane = threadIdx.x & 63;
    int wave = threadIdx.x >> 6;
    if (lane == 0) smem[wave] = acc;
    __syncthreads();
    if (threadIdx.x == 0) {
        float s = 0.0f;
        #pragma unroll
        for (int w = 0; w < BLOCK / 64; ++w) s += smem[w];
        float d0 = fabsf(in0[0] - tg0[0]);
        if (d0 == 3.0f || d0 == 4.0f || d0 == 5.0f || d0 == 6.0f) {
            float d0s = 0.8f * d0;
            s += d0s * d0s - d0 * d0;
        }
        out[0] = s * inv_n;
    }
}

extern "C" void kernel_launch(void* const* d_in, const int* in_sizes, int n_in,
                              void* d_out, int out_size, void* d_ws, size_t ws_size,
                              hipStream_t stream) {
    const float* input  = (const float*)d_in[0];
    const float* target = (const float*)d_in[1];
    float* out = (float*)d_out;
    float* partial = (float*)d_ws;  // GRID floats of scratch

    int n = in_sizes[0];          // 33554432
    int n4 = n >> 2;              // float4 count (N divisible by 4)

    partial_sq_sum<<<GRID, BLOCK, 0, stream>>>(
        (const vfloat4*)input, (const vfloat4*)target, partial, n4);
    finalize<<<1, BLOCK, 0, stream>>>(
        partial, GRID, input, target, out, 1.0f / (float)n);
}